// Round 2
// baseline (127.036 us; speedup 1.0000x reference)
//
#include <hip/hip_runtime.h>
#include <cfloat>

#define BB   1024
#define PP   32
#define NNEG 64
#define NBH  32
#define NNH  32
#define DD   64
#define PSTR 68   // padded LDS row stride in words: 272B, 16B-aligned, 17-word quads

static constexpr float W2c = 0.1f;

// ---------------------------------------------------------------------------
// Mask layout detection (unchanged from passing version) + counter reset.
// ---------------------------------------------------------------------------
__global__ void detect_mask_layout(const unsigned int* __restrict__ mask_words,
                                   int* __restrict__ flag_out,
                                   int* __restrict__ counter) {
    __shared__ int sh_f32, sh_byte;
    if (threadIdx.x == 0) { sh_f32 = 0; sh_byte = 0; *counter = 0; }
    __syncthreads();
    int f32hit = 0, bytehit = 0;
    for (int i = threadIdx.x; i < 8192; i += blockDim.x) {
        unsigned int v = mask_words[i];
        if (v == 0x3f800000u) f32hit = 1;
        else if (v & 0xFFFFFF00u) bytehit = 1;
    }
    if (f32hit)  atomicOr(&sh_f32, 1);
    if (bytehit) atomicOr(&sh_byte, 1);
    __syncthreads();
    if (threadIdx.x == 0)
        *flag_out = sh_f32 ? 2 : (sh_byte ? 1 : 0);
}

__device__ __forceinline__ float parse_mask(const void* p, int flag, int j) {
    if (flag == 1) return ((const unsigned char*)p)[j] ? 1.0f : 0.0f;
    if (flag == 2) return (((const float*)p)[j] != 0.0f) ? 1.0f : 0.0f;
    return ((const int*)p)[j] ? 1.0f : 0.0f;
}

#define DOT4(A, V) ((A).x*(V).x + (A).y*(V).y + (A).z*(V).z + (A).w*(V).w)

// ---------------------------------------------------------------------------
// One block per batch element b; 256 threads (4 waves).
// ---------------------------------------------------------------------------
__global__ __launch_bounds__(256) void loss_kernel(
    const float* __restrict__ u2e, const float* __restrict__ v2e,
    const float* __restrict__ margin_uv, const float* __restrict__ margin_vv,
    const float* __restrict__ margin_uu,
    const int* __restrict__ train_u, const int* __restrict__ pos_idx,
    const int* __restrict__ neg_idx, const int* __restrict__ nb_idx,
    const int* __restrict__ nn_idx,
    const void* __restrict__ pos_mask, const void* __restrict__ neg_mask,
    const void* __restrict__ nb_mask, const void* __restrict__ nn_mask,
    const int* __restrict__ flag_p, float* __restrict__ ws,
    int* __restrict__ counter, float* __restrict__ out) {

    const int b = blockIdx.x;
    const int t = threadIdx.x;
    const int lane = t & 63;
    const int w = t >> 6;
    const int flag = *flag_p;

    __shared__ __align__(16) float p_lds[PP * PSTR];
    __shared__ __align__(16) float n_lds[NNEG * PSTR];
    __shared__ float u_s[DD];
    __shared__ float d1[PP], p2s[PP], d2[NNEG], n2s[NNEG], d1sA[NBH], d2sA[NNH];
    __shared__ float pmf[PP], nmf[NNEG], nbmf[NBH], nnmf[NNH];
    __shared__ float mvp[PP], mv_arr[PP], s_srt[PP], S_suf[PP + 1];
    __shared__ int   pos_i[PP], neg_i[NNEG], nb_i[NBH], nn_i[NNH];
    __shared__ float sc[2];
    __shared__ float red[4][3];
    __shared__ int   is_last;

    const int tu = train_u[b];

    // ---- Phase 0: indices, margins, masks, u row -------------------------
    if (t < DD) u_s[t] = u2e[(size_t)tu * DD + t];
    if (t < PP) {
        int pi = pos_idx[b * PP + t];
        pos_i[t] = pi;
        float mv = margin_vv[pi];
        float pm = parse_mask(pos_mask, flag, b * PP + t);
        mv_arr[t] = mv; pmf[t] = pm;
        mvp[t] = (pm != 0.0f) ? mv : -FLT_MAX;
    } else if (t < PP + NNEG) {
        int j = t - PP;
        neg_i[j] = neg_idx[b * NNEG + j];
        nmf[j]   = parse_mask(neg_mask, flag, b * NNEG + j);
    } else if (t < PP + NNEG + NBH) {
        int j = t - PP - NNEG;
        nb_i[j]  = nb_idx[b * NBH + j];
        nbmf[j]  = parse_mask(nb_mask, flag, b * NBH + j);
    } else if (t < PP + NNEG + NBH + NNH) {
        int j = t - PP - NNEG - NBH;
        nn_i[j]  = nn_idx[b * NNH + j];
        nnmf[j]  = parse_mask(nn_mask, flag, b * NNH + j);
    }
    if (t == 0) { sc[0] = margin_uv[tu]; sc[1] = margin_uu[tu]; }
    __syncthreads();

    // ---- Wave 3: rank-sort masked margins (mvp) into s_srt ---------------
    if (w == 3 && lane < PP) {
        float vj = mvp[lane];
        int r = 0;
        #pragma unroll
        for (int j = 0; j < PP; ++j) {
            float o = mvp[j];
            r += (o < vj || (o == vj && j < lane)) ? 1 : 0;
        }
        s_srt[r] = vj;
    }

    // ---- Phase 1: gather rows, stage p/n, shuffle-reduce distances -------
    const float ue = u_s[lane];
    {   // p rows: 8 per wave
        float e[8];
        #pragma unroll
        for (int q = 0; q < 8; ++q)
            e[q] = v2e[(size_t)pos_i[8 * w + q] * DD + lane];
        #pragma unroll
        for (int q = 0; q < 8; ++q) {
            int r = 8 * w + q;
            p_lds[r * PSTR + lane] = e[q];
            float df = e[q] - ue;
            float sd = df * df, sq = e[q] * e[q];
            #pragma unroll
            for (int m = 1; m < 64; m <<= 1) { sd += __shfl_xor(sd, m); sq += __shfl_xor(sq, m); }
            if (lane == 0) { d1[r] = sd; p2s[r] = sq; }
        }
    }
    {   // n rows: 16 per wave
        float e[16];
        #pragma unroll
        for (int q = 0; q < 16; ++q)
            e[q] = v2e[(size_t)neg_i[16 * w + q] * DD + lane];
        #pragma unroll
        for (int q = 0; q < 16; ++q) {
            int r = 16 * w + q;
            n_lds[r * PSTR + lane] = e[q];
            float df = e[q] - ue;
            float sd = df * df, sq = e[q] * e[q];
            #pragma unroll
            for (int m = 1; m < 64; m <<= 1) { sd += __shfl_xor(sd, m); sq += __shfl_xor(sq, m); }
            if (lane == 0) { d2[r] = sd; n2s[r] = sq; }
        }
    }
    {   // nb / nn rows: 8 + 8 per wave
        float e[8], f[8];
        #pragma unroll
        for (int q = 0; q < 8; ++q) e[q] = u2e[(size_t)nb_i[8 * w + q] * DD + lane];
        #pragma unroll
        for (int q = 0; q < 8; ++q) f[q] = u2e[(size_t)nn_i[8 * w + q] * DD + lane];
        #pragma unroll
        for (int q = 0; q < 8; ++q) {
            float df = e[q] - ue, sd = df * df;
            #pragma unroll
            for (int m = 1; m < 64; m <<= 1) sd += __shfl_xor(sd, m);
            if (lane == 0) d1sA[8 * w + q] = sd;
        }
        #pragma unroll
        for (int q = 0; q < 8; ++q) {
            float df = f[q] - ue, sd = df * df;
            #pragma unroll
            for (int m = 1; m < 64; m <<= 1) sd += __shfl_xor(sd, m);
            if (lane == 0) d2sA[8 * w + q] = sd;
        }
    }
    __syncthreads();

    // ---- Wave 3: suffix sums of sorted margins (S_suf[t] = sum_{j>=t}) ---
    if (w == 3) {
        float y = (lane < PP) ? s_srt[lane] : 0.0f;
        #pragma unroll
        for (int d = 1; d < PP; d <<= 1) {
            float z = __shfl_down(y, d);
            if (lane + d < PP) y += z;
        }
        if (lane < PP) S_suf[lane] = y;
        if (lane == 0) S_suf[PP] = 0.0f;
    }
    __syncthreads();

    // ---- Phase 2: register-blocked 2x4 Gram tiles + closed-form hinge ----
    const float m_u = sc[0], m_s = sc[1];
    const float s31 = s_srt[PP - 1];
    const int kb = t & 15;          // k = kb + 16c
    const int ib = t >> 4;          // i = ib + 16a
    float acc[2][4] = {{0,0,0,0},{0,0,0,0}};
    const float* pr0 = p_lds + ib * PSTR;
    const float* pr1 = p_lds + (ib + 16) * PSTR;
    const float* nr0 = n_lds + kb * PSTR;
    const float* nr1 = n_lds + (kb + 16) * PSTR;
    const float* nr2 = n_lds + (kb + 32) * PSTR;
    const float* nr3 = n_lds + (kb + 48) * PSTR;
    #pragma unroll
    for (int d = 0; d < DD; d += 4) {
        float4 pa = *(const float4*)(pr0 + d);
        float4 pb = *(const float4*)(pr1 + d);
        float4 nA = *(const float4*)(nr0 + d);
        float4 nB = *(const float4*)(nr1 + d);
        float4 nC = *(const float4*)(nr2 + d);
        float4 nD = *(const float4*)(nr3 + d);
        acc[0][0] += DOT4(pa, nA); acc[0][1] += DOT4(pa, nB);
        acc[0][2] += DOT4(pa, nC); acc[0][3] += DOT4(pa, nD);
        acc[1][0] += DOT4(pb, nA); acc[1][1] += DOT4(pb, nB);
        acc[1][2] += DOT4(pb, nC); acc[1][3] += DOT4(pb, nD);
    }

    float loss = 0.0f;
    #pragma unroll
    for (int a = 0; a < 2; ++a) {
        const int i = ib + 16 * a;
        const float d1i = d1[i], p2i = p2s[i], pmi = pmf[i];
        #pragma unroll
        for (int c = 0; c < 4; ++c) {
            const int k = kb + 16 * c;
            const float cc = d1i - (p2i + n2s[k] - 2.0f * acc[a][c]);
            const float v = -cc;
            int t0 = 0;
            #pragma unroll
            for (int st = 16; st > 0; st >>= 1)
                t0 += (s_srt[t0 + st - 1] <= v) ? st : 0;
            t0 += (s31 <= v) ? 1 : 0;
            // sum_j pm_j * relu(mv_j + cc) over sorted active margins
            const float inner = S_suf[t0] + (float)(PP - t0) * cc;
            const float uvh = fmaxf(m_u + d1i - d2[k], 0.0f);
            loss += pmi * nmf[k] * (inner + uvh);
        }
    }

    // uu: 1024 pairs, 4 per thread
    #pragma unroll
    for (int rr = 0; rr < 4; ++rr) {
        int pid = t + 256 * rr;
        int i = pid >> 5, k = pid & 31;
        loss += nbmf[i] * nnmf[k] * fmaxf(m_s + d1sA[i] - d2sA[k], 0.0f);
    }

    // ---- Block reduction --------------------------------------------------
    float a2 = (t < PP) ? mv_arr[t] * pmf[t] : 0.0f;
    float a3 = (t < PP) ? pmf[t] : 0.0f;
    #pragma unroll
    for (int m = 1; m < 64; m <<= 1) {
        loss += __shfl_xor(loss, m);
        a2   += __shfl_xor(a2, m);
        a3   += __shfl_xor(a3, m);
    }
    if (lane == 0) { red[w][0] = loss; red[w][1] = a2; red[w][2] = a3; }
    __syncthreads();
    if (t == 0) {
        float S0 = 0, S2 = 0, S3 = 0;
        for (int i = 0; i < 4; ++i) { S0 += red[i][0]; S2 += red[i][1]; S3 += red[i][2]; }
        ws[0 * BB + b] = S0;
        ws[1 * BB + b] = sc[0];
        ws[2 * BB + b] = S2;
        ws[3 * BB + b] = S3;
        ws[4 * BB + b] = sc[1];
    }

    // ---- Last block finalizes (device-scope fence + atomic ticket) -------
    __threadfence();
    if (t == 0) is_last = (atomicAdd(counter, 1) == BB - 1) ? 1 : 0;
    __syncthreads();
    if (is_last) {
        __threadfence();
        const volatile float* wv = ws;
        float s[5] = {0, 0, 0, 0, 0};
        for (int i2 = t; i2 < BB; i2 += 256)
            #pragma unroll
            for (int a = 0; a < 5; ++a) s[a] += wv[a * BB + i2];
        #pragma unroll
        for (int m = 1; m < 64; m <<= 1)
            #pragma unroll
            for (int a = 0; a < 5; ++a) s[a] += __shfl_xor(s[a], m);
        __shared__ float red5[4][5];
        if (lane == 0)
            #pragma unroll
            for (int a = 0; a < 5; ++a) red5[w][a] = s[a];
        __syncthreads();
        if (t == 0) {
            float S[5];
            #pragma unroll
            for (int a = 0; a < 5; ++a) {
                S[a] = 0;
                for (int i = 0; i < 4; ++i) S[a] += red5[i][a];
            }
            float loss_am = S[1] / (float)BB + S[2] / S[3] + S[4] / (float)BB;
            out[0] = S[0] + W2c * loss_am;
        }
    }
}

extern "C" void kernel_launch(void* const* d_in, const int* in_sizes, int n_in,
                              void* d_out, int out_size, void* d_ws, size_t ws_size,
                              hipStream_t stream) {
    const float* u2e       = (const float*)d_in[0];
    const float* v2e       = (const float*)d_in[1];
    const float* margin_uv = (const float*)d_in[2];
    const float* margin_vv = (const float*)d_in[3];
    const float* margin_uu = (const float*)d_in[4];
    const int*   train_u   = (const int*)d_in[5];
    const int*   pos_idx   = (const int*)d_in[6];
    const int*   neg_idx   = (const int*)d_in[7];
    const int*   nb_idx    = (const int*)d_in[8];
    const int*   nn_idx    = (const int*)d_in[9];
    const void*  pos_mask  = d_in[10];
    const void*  neg_mask  = d_in[11];
    const void*  nb_mask   = d_in[12];
    const void*  nn_mask   = d_in[13];

    float* ws      = (float*)d_ws;
    int*   flag_p  = (int*)(ws + 5 * BB);
    int*   counter = flag_p + 1;
    float* out     = (float*)d_out;

    detect_mask_layout<<<1, 256, 0, stream>>>((const unsigned int*)pos_mask, flag_p, counter);
    loss_kernel<<<BB, 256, 0, stream>>>(u2e, v2e, margin_uv, margin_vv, margin_uu,
                                        train_u, pos_idx, neg_idx, nb_idx, nn_idx,
                                        pos_mask, neg_mask, nb_mask, nn_mask,
                                        flag_p, ws, counter, out);
}

// Round 3
// 48.673 us; speedup vs baseline: 2.6100x; 2.6100x over previous
//
#include <hip/hip_runtime.h>
#include <cfloat>

#define BB   1024
#define PP   32
#define NNEG 64
#define NBH  32
#define NNH  32
#define DD   64
#define PSTR 68   // padded LDS row stride in words: 272B, 16B-aligned

static constexpr float W2c = 0.1f;

// ---------------------------------------------------------------------------
// Mask layout detection: byte bool (flag=1), int32 0/1 (flag=0), f32 (flag=2).
// ---------------------------------------------------------------------------
__global__ void detect_mask_layout(const unsigned int* __restrict__ mask_words,
                                   int* __restrict__ flag_out) {
    __shared__ int sh_f32, sh_byte;
    if (threadIdx.x == 0) { sh_f32 = 0; sh_byte = 0; }
    __syncthreads();
    int f32hit = 0, bytehit = 0;
    for (int i = threadIdx.x; i < 8192; i += blockDim.x) {
        unsigned int v = mask_words[i];
        if (v == 0x3f800000u) f32hit = 1;
        else if (v & 0xFFFFFF00u) bytehit = 1;
    }
    if (f32hit)  atomicOr(&sh_f32, 1);
    if (bytehit) atomicOr(&sh_byte, 1);
    __syncthreads();
    if (threadIdx.x == 0)
        *flag_out = sh_f32 ? 2 : (sh_byte ? 1 : 0);
}

__device__ __forceinline__ float parse_mask(const void* p, int flag, int j) {
    if (flag == 1) return ((const unsigned char*)p)[j] ? 1.0f : 0.0f;
    if (flag == 2) return (((const float*)p)[j] != 0.0f) ? 1.0f : 0.0f;
    return ((const int*)p)[j] ? 1.0f : 0.0f;
}

#define DOT4(A, V) ((A).x*(V).x + (A).y*(V).y + (A).z*(V).z + (A).w*(V).w)

// ---------------------------------------------------------------------------
// One block per batch element b; 256 threads (4 waves). No device-scope
// fences anywhere (1024x buffer_wbl2 was the round-2 regression).
// ---------------------------------------------------------------------------
__global__ __launch_bounds__(256) void loss_kernel(
    const float* __restrict__ u2e, const float* __restrict__ v2e,
    const float* __restrict__ margin_uv, const float* __restrict__ margin_vv,
    const float* __restrict__ margin_uu,
    const int* __restrict__ train_u, const int* __restrict__ pos_idx,
    const int* __restrict__ neg_idx, const int* __restrict__ nb_idx,
    const int* __restrict__ nn_idx,
    const void* __restrict__ pos_mask, const void* __restrict__ neg_mask,
    const void* __restrict__ nb_mask, const void* __restrict__ nn_mask,
    const int* __restrict__ flag_p, float* __restrict__ ws) {

    const int b = blockIdx.x;
    const int t = threadIdx.x;
    const int lane = t & 63;
    const int w = t >> 6;
    const int flag = *flag_p;

    __shared__ __align__(16) float p_lds[PP * PSTR];
    __shared__ __align__(16) float n_lds[NNEG * PSTR];
    __shared__ float u_s[DD];
    __shared__ float d1[PP], p2s[PP], d2[NNEG], n2s[NNEG], d1sA[NBH], d2sA[NNH];
    __shared__ float pmf[PP], nmf[NNEG], nbmf[NBH], nnmf[NNH];
    __shared__ float mvp[PP], mv_arr[PP], s_srt[PP], S_suf[PP + 1];
    __shared__ int   pos_i[PP], neg_i[NNEG], nb_i[NBH], nn_i[NNH];
    __shared__ float sc[2];
    __shared__ float red[4][3];

    const int tu = train_u[b];

    // ---- Phase 0: indices, margins, masks, u row -------------------------
    if (t < DD) u_s[t] = u2e[(size_t)tu * DD + t];
    if (t < PP) {
        int pi = pos_idx[b * PP + t];
        pos_i[t] = pi;
        float mv = margin_vv[pi];
        float pm = parse_mask(pos_mask, flag, b * PP + t);
        mv_arr[t] = mv; pmf[t] = pm;
        mvp[t] = (pm != 0.0f) ? mv : -FLT_MAX;
    } else if (t < PP + NNEG) {
        int j = t - PP;
        neg_i[j] = neg_idx[b * NNEG + j];
        nmf[j]   = parse_mask(neg_mask, flag, b * NNEG + j);
    } else if (t < PP + NNEG + NBH) {
        int j = t - PP - NNEG;
        nb_i[j]  = nb_idx[b * NBH + j];
        nbmf[j]  = parse_mask(nb_mask, flag, b * NBH + j);
    } else if (t < PP + NNEG + NBH + NNH) {
        int j = t - PP - NNEG - NBH;
        nn_i[j]  = nn_idx[b * NNH + j];
        nnmf[j]  = parse_mask(nn_mask, flag, b * NNH + j);
    }
    if (t == 0) { sc[0] = margin_uv[tu]; sc[1] = margin_uu[tu]; }
    __syncthreads();

    // ---- Wave 3: rank-sort masked margins (mvp) into s_srt ---------------
    if (w == 3 && lane < PP) {
        float vj = mvp[lane];
        int r = 0;
        #pragma unroll
        for (int j = 0; j < PP; ++j) {
            float o = mvp[j];
            r += (o < vj || (o == vj && j < lane)) ? 1 : 0;
        }
        s_srt[r] = vj;
    }

    // ---- Phase 1: gather rows, stage p/n, shuffle-reduce distances -------
    const float ue = u_s[lane];
    {   // p rows: 8 per wave
        float e[8];
        #pragma unroll
        for (int q = 0; q < 8; ++q)
            e[q] = v2e[(size_t)pos_i[8 * w + q] * DD + lane];
        #pragma unroll
        for (int q = 0; q < 8; ++q) {
            int r = 8 * w + q;
            p_lds[r * PSTR + lane] = e[q];
            float df = e[q] - ue;
            float sd = df * df, sq = e[q] * e[q];
            #pragma unroll
            for (int m = 1; m < 64; m <<= 1) { sd += __shfl_xor(sd, m); sq += __shfl_xor(sq, m); }
            if (lane == 0) { d1[r] = sd; p2s[r] = sq; }
        }
    }
    {   // n rows: 16 per wave
        float e[16];
        #pragma unroll
        for (int q = 0; q < 16; ++q)
            e[q] = v2e[(size_t)neg_i[16 * w + q] * DD + lane];
        #pragma unroll
        for (int q = 0; q < 16; ++q) {
            int r = 16 * w + q;
            n_lds[r * PSTR + lane] = e[q];
            float df = e[q] - ue;
            float sd = df * df, sq = e[q] * e[q];
            #pragma unroll
            for (int m = 1; m < 64; m <<= 1) { sd += __shfl_xor(sd, m); sq += __shfl_xor(sq, m); }
            if (lane == 0) { d2[r] = sd; n2s[r] = sq; }
        }
    }
    {   // nb / nn rows: 8 + 8 per wave
        float e[8], f[8];
        #pragma unroll
        for (int q = 0; q < 8; ++q) e[q] = u2e[(size_t)nb_i[8 * w + q] * DD + lane];
        #pragma unroll
        for (int q = 0; q < 8; ++q) f[q] = u2e[(size_t)nn_i[8 * w + q] * DD + lane];
        #pragma unroll
        for (int q = 0; q < 8; ++q) {
            float df = e[q] - ue, sd = df * df;
            #pragma unroll
            for (int m = 1; m < 64; m <<= 1) sd += __shfl_xor(sd, m);
            if (lane == 0) d1sA[8 * w + q] = sd;
        }
        #pragma unroll
        for (int q = 0; q < 8; ++q) {
            float df = f[q] - ue, sd = df * df;
            #pragma unroll
            for (int m = 1; m < 64; m <<= 1) sd += __shfl_xor(sd, m);
            if (lane == 0) d2sA[8 * w + q] = sd;
        }
    }
    __syncthreads();

    // ---- Wave 3: suffix sums of sorted margins (S_suf[t] = sum_{j>=t}) ---
    if (w == 3) {
        float y = (lane < PP) ? s_srt[lane] : 0.0f;
        #pragma unroll
        for (int d = 1; d < PP; d <<= 1) {
            float z = __shfl_down(y, d);
            if (lane + d < PP) y += z;
        }
        if (lane < PP) S_suf[lane] = y;
        if (lane == 0) S_suf[PP] = 0.0f;
    }
    __syncthreads();

    // ---- Phase 2: register-blocked 2x4 Gram tiles + closed-form hinge ----
    const float m_u = sc[0], m_s = sc[1];
    const float s31 = s_srt[PP - 1];
    const int kb = t & 15;          // k = kb + 16c
    const int ib = t >> 4;          // i = ib + 16a
    float acc[2][4] = {{0,0,0,0},{0,0,0,0}};
    const float* pr0 = p_lds + ib * PSTR;
    const float* pr1 = p_lds + (ib + 16) * PSTR;
    const float* nr0 = n_lds + kb * PSTR;
    const float* nr1 = n_lds + (kb + 16) * PSTR;
    const float* nr2 = n_lds + (kb + 32) * PSTR;
    const float* nr3 = n_lds + (kb + 48) * PSTR;
    #pragma unroll
    for (int d = 0; d < DD; d += 4) {
        float4 pa = *(const float4*)(pr0 + d);
        float4 pb = *(const float4*)(pr1 + d);
        float4 nA = *(const float4*)(nr0 + d);
        float4 nB = *(const float4*)(nr1 + d);
        float4 nC = *(const float4*)(nr2 + d);
        float4 nD = *(const float4*)(nr3 + d);
        acc[0][0] += DOT4(pa, nA); acc[0][1] += DOT4(pa, nB);
        acc[0][2] += DOT4(pa, nC); acc[0][3] += DOT4(pa, nD);
        acc[1][0] += DOT4(pb, nA); acc[1][1] += DOT4(pb, nB);
        acc[1][2] += DOT4(pb, nC); acc[1][3] += DOT4(pb, nD);
    }

    float loss = 0.0f;
    #pragma unroll
    for (int a = 0; a < 2; ++a) {
        const int i = ib + 16 * a;
        const float d1i = d1[i], p2i = p2s[i], pmi = pmf[i];
        #pragma unroll
        for (int c = 0; c < 4; ++c) {
            const int k = kb + 16 * c;
            const float cc = d1i - (p2i + n2s[k] - 2.0f * acc[a][c]);
            const float v = -cc;
            int t0 = 0;
            #pragma unroll
            for (int st = 16; st > 0; st >>= 1)
                t0 += (s_srt[t0 + st - 1] <= v) ? st : 0;
            t0 += (s31 <= v) ? 1 : 0;
            // sum_j pm_j * relu(mv_j + cc) over sorted active margins
            const float inner = S_suf[t0] + (float)(PP - t0) * cc;
            const float uvh = fmaxf(m_u + d1i - d2[k], 0.0f);
            loss += pmi * nmf[k] * (inner + uvh);
        }
    }

    // uu: 1024 pairs, 4 per thread
    #pragma unroll
    for (int rr = 0; rr < 4; ++rr) {
        int pid = t + 256 * rr;
        int i = pid >> 5, k = pid & 31;
        loss += nbmf[i] * nnmf[k] * fmaxf(m_s + d1sA[i] - d2sA[k], 0.0f);
    }

    // ---- Block reduction --------------------------------------------------
    float a2 = (t < PP) ? mv_arr[t] * pmf[t] : 0.0f;
    float a3 = (t < PP) ? pmf[t] : 0.0f;
    #pragma unroll
    for (int m = 1; m < 64; m <<= 1) {
        loss += __shfl_xor(loss, m);
        a2   += __shfl_xor(a2, m);
        a3   += __shfl_xor(a3, m);
    }
    if (lane == 0) { red[w][0] = loss; red[w][1] = a2; red[w][2] = a3; }
    __syncthreads();
    if (t == 0) {
        float S0 = 0, S2 = 0, S3 = 0;
        for (int i = 0; i < 4; ++i) { S0 += red[i][0]; S2 += red[i][1]; S3 += red[i][2]; }
        ws[0 * BB + b] = S0;
        ws[1 * BB + b] = sc[0];
        ws[2 * BB + b] = S2;
        ws[3 * BB + b] = S3;
        ws[4 * BB + b] = sc[1];
    }
}

// ---------------------------------------------------------------------------
// Finalize: deterministic tree reduction of the 5 per-block partial arrays.
// ---------------------------------------------------------------------------
__global__ __launch_bounds__(256) void finalize_kernel(const float* __restrict__ ws,
                                                       float* __restrict__ out) {
    __shared__ float red[4][5];
    const int t = threadIdx.x, lane = t & 63, w = t >> 6;
    float s[5] = {0, 0, 0, 0, 0};
    for (int i = t; i < BB; i += 256)
        #pragma unroll
        for (int a = 0; a < 5; ++a) s[a] += ws[a * BB + i];
    #pragma unroll
    for (int m = 1; m < 64; m <<= 1)
        #pragma unroll
        for (int a = 0; a < 5; ++a) s[a] += __shfl_xor(s[a], m);
    if (lane == 0)
        #pragma unroll
        for (int a = 0; a < 5; ++a) red[w][a] = s[a];
    __syncthreads();
    if (t == 0) {
        float S[5];
        #pragma unroll
        for (int a = 0; a < 5; ++a) {
            S[a] = 0;
            for (int i = 0; i < 4; ++i) S[a] += red[i][a];
        }
        float loss_am = S[1] / (float)BB + S[2] / S[3] + S[4] / (float)BB;
        out[0] = S[0] + W2c * loss_am;
    }
}

extern "C" void kernel_launch(void* const* d_in, const int* in_sizes, int n_in,
                              void* d_out, int out_size, void* d_ws, size_t ws_size,
                              hipStream_t stream) {
    const float* u2e       = (const float*)d_in[0];
    const float* v2e       = (const float*)d_in[1];
    const float* margin_uv = (const float*)d_in[2];
    const float* margin_vv = (const float*)d_in[3];
    const float* margin_uu = (const float*)d_in[4];
    const int*   train_u   = (const int*)d_in[5];
    const int*   pos_idx   = (const int*)d_in[6];
    const int*   neg_idx   = (const int*)d_in[7];
    const int*   nb_idx    = (const int*)d_in[8];
    const int*   nn_idx    = (const int*)d_in[9];
    const void*  pos_mask  = d_in[10];
    const void*  neg_mask  = d_in[11];
    const void*  nb_mask   = d_in[12];
    const void*  nn_mask   = d_in[13];

    float* ws      = (float*)d_ws;
    int*   flag_p  = (int*)(ws + 5 * BB);
    float* out     = (float*)d_out;

    detect_mask_layout<<<1, 256, 0, stream>>>((const unsigned int*)pos_mask, flag_p);
    loss_kernel<<<BB, 256, 0, stream>>>(u2e, v2e, margin_uv, margin_vv, margin_uu,
                                        train_u, pos_idx, neg_idx, nb_idx, nn_idx,
                                        pos_mask, neg_mask, nb_mask, nn_mask,
                                        flag_p, ws);
    finalize_kernel<<<1, 256, 0, stream>>>(ws, out);
}

// Round 4
// 24.645 us; speedup vs baseline: 5.1547x; 1.9750x over previous
//
#include <hip/hip_runtime.h>
#include <cfloat>

#define BB   1024
#define PP   32
#define NNEG 64
#define NBH  32
#define NNH  32
#define DD   64
#define PSTR 68   // padded LDS row stride in words: 272B, 16B-aligned

static constexpr float W2c = 0.1f;

__device__ __forceinline__ float parse_mask(const void* p, int flag, int j) {
    if (flag == 1) return ((const unsigned char*)p)[j] ? 1.0f : 0.0f;
    if (flag == 2) return (((const float*)p)[j] != 0.0f) ? 1.0f : 0.0f;
    return ((const int*)p)[j] ? 1.0f : 0.0f;
}

#define DOT4(A, V) ((A).x*(V).x + (A).y*(V).y + (A).z*(V).z + (A).w*(V).w)

// ---------------------------------------------------------------------------
// One block per batch element b; 256 threads (4 waves).
// Phase 1 has ZERO cross-lane shuffles (they were ~half the kernel):
// stage p/n via float4 ds_write, row stats by row-owner threads.
// ---------------------------------------------------------------------------
__global__ __launch_bounds__(256) void loss_kernel(
    const float* __restrict__ u2e, const float* __restrict__ v2e,
    const float* __restrict__ margin_uv, const float* __restrict__ margin_vv,
    const float* __restrict__ margin_uu,
    const int* __restrict__ train_u, const int* __restrict__ pos_idx,
    const int* __restrict__ neg_idx, const int* __restrict__ nb_idx,
    const int* __restrict__ nn_idx,
    const void* __restrict__ pos_mask, const void* __restrict__ neg_mask,
    const void* __restrict__ nb_mask, const void* __restrict__ nn_mask,
    float* __restrict__ ws) {

    const int b = blockIdx.x;
    const int t = threadIdx.x;
    const int lane = t & 63;
    const int w = t >> 6;

    __shared__ __align__(16) float pn_lds[96 * PSTR];  // rows 0..31 p, 32..95 n
    __shared__ __align__(16) float u_s[DD];
    __shared__ float d1[PP], p2s[PP], d2[NNEG], n2s[NNEG], d1sA[NBH], d2sA[NNH];
    __shared__ float pmf[PP], nmf[NNEG], nbmf[NBH], nnmf[NNH];
    __shared__ float mvp[PP], mv_arr[PP], s_srt[PP], S_suf[PP + 1];
    __shared__ int   pos_i[PP], neg_i[NNEG], nb_i[NBH], nn_i[NNH];
    __shared__ float sc[2];
    __shared__ float red[4][3];
    __shared__ int   wflags[4][2];

    const int tu = train_u[b];

    // ---- Step 1: mask-layout sniff (first 1KB of pos_mask), indices, u ---
    {
        unsigned int mw = ((const unsigned int*)pos_mask)[t];  // t<256, safe in all layouts
        int f32hit  = (mw == 0x3f800000u) ? 1 : 0;
        int bytehit = (!f32hit && (mw & 0xFFFFFF00u)) ? 1 : 0;
        int wf = __any(f32hit) ? 1 : 0;
        int wb = __any(bytehit) ? 1 : 0;
        if (lane == 0) { wflags[w][0] = wf; wflags[w][1] = wb; }
    }
    if (t < DD) u_s[t] = u2e[(size_t)tu * DD + t];
    if (t < PP)              pos_i[t]       = pos_idx[b * PP + t];
    else if (t < 96)         neg_i[t - PP]  = neg_idx[b * NNEG + (t - PP)];
    else if (t < 128)        nb_i[t - 96]   = nb_idx[b * NBH + (t - 96)];
    else if (t < 160)        nn_i[t - 128]  = nn_idx[b * NNH + (t - 128)];
    if (t == 0) { sc[0] = margin_uv[tu]; sc[1] = margin_uu[tu]; }
    __syncthreads();

    const int flag = (wflags[0][0] | wflags[1][0] | wflags[2][0] | wflags[3][0]) ? 2
                   : ((wflags[0][1] | wflags[1][1] | wflags[2][1] | wflags[3][1]) ? 1 : 0);

    // ---- Step 2: stage p/n (6 float4 chunks/thread), masks, nb/nn stats --
    float4 ch[6]; int dst[6];
    #pragma unroll
    for (int r = 0; r < 6; ++r) {
        int c = t + 256 * r;          // 1536 chunks = 96 rows x 16
        int row = c >> 4, q = c & 15;
        int gidx = (row < PP) ? pos_i[row] : neg_i[row - PP];
        ch[r]  = *(const float4*)(v2e + (size_t)gidx * DD + 4 * q);
        dst[r] = row * PSTR + 4 * q;
    }
    if (t < PP) {
        float pm = parse_mask(pos_mask, flag, b * PP + t);
        float mv = margin_vv[pos_i[t]];
        pmf[t] = pm; mv_arr[t] = mv;
        mvp[t] = (pm != 0.0f) ? mv : -FLT_MAX;
    } else if (t < 96) {
        nmf[t - PP] = parse_mask(neg_mask, flag, b * NNEG + (t - PP));
    } else if (t < 128) {
        nbmf[t - 96] = parse_mask(nb_mask, flag, b * NBH + (t - 96));
    } else if (t < 160) {
        nnmf[t - 128] = parse_mask(nn_mask, flag, b * NNH + (t - 128));
    }
    // nb/nn row-owner stats straight from global (rows are L2/L3-resident)
    if (t >= 96 && t < 160) {
        const int i = t - 96;
        const float* rowp = (i < NBH) ? (u2e + (size_t)nb_i[i] * DD)
                                      : (u2e + (size_t)nn_i[i - NBH] * DD);
        float s = 0.0f;
        #pragma unroll
        for (int q = 0; q < 16; ++q) {
            float4 e  = *(const float4*)(rowp + 4 * q);
            float4 uu = *(const float4*)(u_s + 4 * q);
            float dx = e.x - uu.x, dy = e.y - uu.y, dz = e.z - uu.z, dw = e.w - uu.w;
            s += dx * dx + dy * dy + dz * dz + dw * dw;
        }
        if (i < NBH) d1sA[i] = s; else d2sA[i - NBH] = s;
    }
    #pragma unroll
    for (int r = 0; r < 6; ++r)
        *(float4*)(pn_lds + dst[r]) = ch[r];
    __syncthreads();

    // ---- Step 3: p/n row stats (owners t<96) ; wave 3: sort + suffix sums -
    if (t < 96) {
        const float* rp = pn_lds + t * PSTR;
        float sd = 0.0f, sq = 0.0f;
        #pragma unroll
        for (int q = 0; q < 16; ++q) {
            float4 e  = *(const float4*)(rp + 4 * q);
            float4 uu = *(const float4*)(u_s + 4 * q);
            float dx = e.x - uu.x, dy = e.y - uu.y, dz = e.z - uu.z, dw = e.w - uu.w;
            sd += dx * dx + dy * dy + dz * dz + dw * dw;
            sq += e.x * e.x + e.y * e.y + e.z * e.z + e.w * e.w;
        }
        if (t < PP) { d1[t] = sd; p2s[t] = sq; }
        else        { d2[t - PP] = sd; n2s[t - PP] = sq; }
    } else if (w == 3) {
        if (lane < PP) {
            float vj = mvp[lane];
            int r = 0;
            #pragma unroll
            for (int j = 0; j < PP; ++j) {
                float o = mvp[j];
                r += (o < vj || (o == vj && j < lane)) ? 1 : 0;
            }
            s_srt[r] = vj;
        }
        __threadfence_block();   // order scatter-write -> gather-read (same wave)
        float y = (lane < PP) ? s_srt[lane] : 0.0f;
        #pragma unroll
        for (int d = 1; d < PP; d <<= 1) {
            float z = __shfl_down(y, d);
            if (lane + d < PP) y += z;
        }
        if (lane < PP) S_suf[lane] = y;
        if (lane == 0) S_suf[PP] = 0.0f;
    }
    __syncthreads();

    // ---- Phase 2: register-blocked 2x4 Gram tiles + closed-form hinge ----
    const float m_u = sc[0], m_s = sc[1];
    const float s31 = s_srt[PP - 1];
    const int kb = t & 15;          // k = kb + 16c
    const int ib = t >> 4;          // i = ib + 16a
    float acc[2][4] = {{0,0,0,0},{0,0,0,0}};
    const float* pr0 = pn_lds + ib * PSTR;
    const float* pr1 = pn_lds + (ib + 16) * PSTR;
    const float* nr0 = pn_lds + (32 + kb) * PSTR;
    const float* nr1 = pn_lds + (32 + kb + 16) * PSTR;
    const float* nr2 = pn_lds + (32 + kb + 32) * PSTR;
    const float* nr3 = pn_lds + (32 + kb + 48) * PSTR;
    #pragma unroll
    for (int d = 0; d < DD; d += 4) {
        float4 pa = *(const float4*)(pr0 + d);
        float4 pb = *(const float4*)(pr1 + d);
        float4 nA = *(const float4*)(nr0 + d);
        float4 nB = *(const float4*)(nr1 + d);
        float4 nC = *(const float4*)(nr2 + d);
        float4 nD = *(const float4*)(nr3 + d);
        acc[0][0] += DOT4(pa, nA); acc[0][1] += DOT4(pa, nB);
        acc[0][2] += DOT4(pa, nC); acc[0][3] += DOT4(pa, nD);
        acc[1][0] += DOT4(pb, nA); acc[1][1] += DOT4(pb, nB);
        acc[1][2] += DOT4(pb, nC); acc[1][3] += DOT4(pb, nD);
    }

    float loss = 0.0f;
    #pragma unroll
    for (int a = 0; a < 2; ++a) {
        const int i = ib + 16 * a;
        const float d1i = d1[i], p2i = p2s[i], pmi = pmf[i];
        #pragma unroll
        for (int c = 0; c < 4; ++c) {
            const int k = kb + 16 * c;
            const float cc = d1i - (p2i + n2s[k] - 2.0f * acc[a][c]);
            const float v = -cc;
            int t0 = 0;
            #pragma unroll
            for (int st = 16; st > 0; st >>= 1)
                t0 += (s_srt[t0 + st - 1] <= v) ? st : 0;
            t0 += (s31 <= v) ? 1 : 0;
            const float inner = S_suf[t0] + (float)(PP - t0) * cc;
            const float uvh = fmaxf(m_u + d1i - d2[k], 0.0f);
            loss += pmi * nmf[k] * (inner + uvh);
        }
    }

    // uu: 1024 pairs, 4 per thread
    #pragma unroll
    for (int rr = 0; rr < 4; ++rr) {
        int pid = t + 256 * rr;
        int i = pid >> 5, k = pid & 31;
        loss += nbmf[i] * nnmf[k] * fmaxf(m_s + d1sA[i] - d2sA[k], 0.0f);
    }

    // ---- Block reduction --------------------------------------------------
    float a2 = (t < PP) ? mv_arr[t] * pmf[t] : 0.0f;
    float a3 = (t < PP) ? pmf[t] : 0.0f;
    #pragma unroll
    for (int m = 1; m < 64; m <<= 1) {
        loss += __shfl_xor(loss, m);
        a2   += __shfl_xor(a2, m);
        a3   += __shfl_xor(a3, m);
    }
    if (lane == 0) { red[w][0] = loss; red[w][1] = a2; red[w][2] = a3; }
    __syncthreads();
    if (t == 0) {
        float S0 = 0, S2 = 0, S3 = 0;
        for (int i = 0; i < 4; ++i) { S0 += red[i][0]; S2 += red[i][1]; S3 += red[i][2]; }
        ws[0 * BB + b] = S0;
        ws[1 * BB + b] = sc[0];
        ws[2 * BB + b] = S2;
        ws[3 * BB + b] = S3;
        ws[4 * BB + b] = sc[1];
    }
}

// ---------------------------------------------------------------------------
// Finalize: deterministic tree reduction of the 5 per-block partial arrays.
// ---------------------------------------------------------------------------
__global__ __launch_bounds__(256) void finalize_kernel(const float* __restrict__ ws,
                                                       float* __restrict__ out) {
    __shared__ float red[4][5];
    const int t = threadIdx.x, lane = t & 63, w = t >> 6;
    float s[5] = {0, 0, 0, 0, 0};
    for (int i = t; i < BB; i += 256)
        #pragma unroll
        for (int a = 0; a < 5; ++a) s[a] += ws[a * BB + i];
    #pragma unroll
    for (int m = 1; m < 64; m <<= 1)
        #pragma unroll
        for (int a = 0; a < 5; ++a) s[a] += __shfl_xor(s[a], m);
    if (lane == 0)
        #pragma unroll
        for (int a = 0; a < 5; ++a) red[w][a] = s[a];
    __syncthreads();
    if (t == 0) {
        float S[5];
        #pragma unroll
        for (int a = 0; a < 5; ++a) {
            S[a] = 0;
            for (int i = 0; i < 4; ++i) S[a] += red[i][a];
        }
        float loss_am = S[1] / (float)BB + S[2] / S[3] + S[4] / (float)BB;
        out[0] = S[0] + W2c * loss_am;
    }
}

extern "C" void kernel_launch(void* const* d_in, const int* in_sizes, int n_in,
                              void* d_out, int out_size, void* d_ws, size_t ws_size,
                              hipStream_t stream) {
    const float* u2e       = (const float*)d_in[0];
    const float* v2e       = (const float*)d_in[1];
    const float* margin_uv = (const float*)d_in[2];
    const float* margin_vv = (const float*)d_in[3];
    const float* margin_uu = (const float*)d_in[4];
    const int*   train_u   = (const int*)d_in[5];
    const int*   pos_idx   = (const int*)d_in[6];
    const int*   neg_idx   = (const int*)d_in[7];
    const int*   nb_idx    = (const int*)d_in[8];
    const int*   nn_idx    = (const int*)d_in[9];
    const void*  pos_mask  = d_in[10];
    const void*  neg_mask  = d_in[11];
    const void*  nb_mask   = d_in[12];
    const void*  nn_mask   = d_in[13];

    float* ws  = (float*)d_ws;
    float* out = (float*)d_out;

    loss_kernel<<<BB, 256, 0, stream>>>(u2e, v2e, margin_uv, margin_vv, margin_uu,
                                        train_u, pos_idx, neg_idx, nb_idx, nn_idx,
                                        pos_mask, neg_mask, nb_mask, nn_mask, ws);
    finalize_kernel<<<1, 256, 0, stream>>>(ws, out);
}

// Round 5
// 21.496 us; speedup vs baseline: 5.9098x; 1.1465x over previous
//
#include <hip/hip_runtime.h>
#include <cfloat>

#define BB   1024
#define PP   32
#define NNEG 64
#define DD   64
#define BSTR 72   // bf16 LDS row stride (144 B, 16B-aligned)
#define SSTR 66   // s_lds row stride in floats

static constexpr float W2c = 0.1f;

typedef __attribute__((ext_vector_type(8)))  short bf16x8;
typedef __attribute__((ext_vector_type(16))) float f32x16;

__device__ __forceinline__ short f2bf(float f) {   // RNE fp32->bf16
    unsigned u = __float_as_uint(f);
    unsigned r = (u + 0x7fffu + ((u >> 16) & 1u)) >> 16;
    return (short)r;
}

__device__ __forceinline__ float parse_mask(const void* p, int flag, int j) {
    if (flag == 1) return ((const unsigned char*)p)[j] ? 1.0f : 0.0f;
    if (flag == 2) return (((const float*)p)[j] != 0.0f) ? 1.0f : 0.0f;
    return ((const int*)p)[j] ? 1.0f : 0.0f;
}

// ---------------------------------------------------------------------------
// One block per batch element b; 256 threads (4 waves).
// Gram matrix P·N^T via 2 waves x 4 v_mfma_f32_32x32x16_bf16 (replaces
// 393 KB/block of ds_read_b128 re-reads — the round-4 LDS-pipe bottleneck).
// d1/d2/p2/n2 stats stay exact fp32 (global re-reads, L2-hot).
// ---------------------------------------------------------------------------
__global__ __launch_bounds__(256) void loss_kernel(
    const float* __restrict__ u2e, const float* __restrict__ v2e,
    const float* __restrict__ margin_uv, const float* __restrict__ margin_vv,
    const float* __restrict__ margin_uu,
    const int* __restrict__ train_u, const int* __restrict__ pos_idx,
    const int* __restrict__ neg_idx, const int* __restrict__ nb_idx,
    const int* __restrict__ nn_idx,
    const void* __restrict__ pos_mask, const void* __restrict__ neg_mask,
    const void* __restrict__ nb_mask, const void* __restrict__ nn_mask,
    float* __restrict__ ws) {

    const int b = blockIdx.x;
    const int t = threadIdx.x;
    const int lane = t & 63;
    const int w = t >> 6;

    __shared__ __align__(16) short pn_bf[96 * BSTR];   // rows 0..31 p, 32..95 n (bf16)
    __shared__ __align__(16) float s_lds[PP * SSTR];   // Gram output S[i][k]
    __shared__ __align__(16) float u_s[DD];
    __shared__ float d1[PP], p2s[PP], d2[NNEG], n2s[NNEG], d1sA[PP], d2sA[PP];
    __shared__ float pmf[PP], nmf[NNEG], nbmf[PP], nnmf[PP];
    __shared__ float mvp[PP], mv_arr[PP], s_srt[PP], S_suf[PP + 1];
    __shared__ int   pos_i[PP], neg_i[NNEG], nb_i[PP], nn_i[PP];
    __shared__ float sc[2];
    __shared__ float red[4][3];
    __shared__ int   wflags[4][2];

    const int tu = train_u[b];

    // ---- Step 1: mask-layout sniff, indices, u row, margins --------------
    {
        unsigned int mw = ((const unsigned int*)pos_mask)[t];  // first 1KB, safe in all layouts
        int f32hit  = (mw == 0x3f800000u) ? 1 : 0;
        int bytehit = (!f32hit && (mw & 0xFFFFFF00u)) ? 1 : 0;
        int wf = __any(f32hit) ? 1 : 0;
        int wb = __any(bytehit) ? 1 : 0;
        if (lane == 0) { wflags[w][0] = wf; wflags[w][1] = wb; }
    }
    if (t < DD) u_s[t] = u2e[(size_t)tu * DD + t];
    if (t < PP)              pos_i[t]       = pos_idx[b * PP + t];
    else if (t < 96)         neg_i[t - PP]  = neg_idx[b * NNEG + (t - PP)];
    else if (t < 128)        nb_i[t - 96]   = nb_idx[b * PP + (t - 96)];
    else if (t < 160)        nn_i[t - 128]  = nn_idx[b * PP + (t - 128)];
    if (t == 0) { sc[0] = margin_uv[tu]; sc[1] = margin_uu[tu]; }
    __syncthreads();

    const int flag = (wflags[0][0] | wflags[1][0] | wflags[2][0] | wflags[3][0]) ? 2
                   : ((wflags[0][1] | wflags[1][1] | wflags[2][1] | wflags[3][1]) ? 1 : 0);

    // ---- Step 2: gather p/n chunks, masks, nb/nn stats (quartered) -------
    float4 ch[6]; int dstRow[6], dstQ[6];
    #pragma unroll
    for (int r = 0; r < 6; ++r) {
        int c = t + 256 * r;          // 1536 chunks = 96 rows x 16
        int row = c >> 4, q = c & 15;
        int gidx = (row < PP) ? pos_i[row] : neg_i[row - PP];
        ch[r]   = *(const float4*)(v2e + (size_t)gidx * DD + 4 * q);
        dstRow[r] = row; dstQ[r] = q;
    }
    if (t < PP) {
        float pm = parse_mask(pos_mask, flag, b * PP + t);
        float mv = margin_vv[pos_i[t]];
        pmf[t] = pm; mv_arr[t] = mv;
        mvp[t] = (pm != 0.0f) ? mv : -FLT_MAX;
    } else if (t < 96) {
        nmf[t - PP] = parse_mask(neg_mask, flag, b * NNEG + (t - PP));
    } else if (t < 128) {
        nbmf[t - 96] = parse_mask(nb_mask, flag, b * PP + (t - 96));
    } else if (t < 160) {
        nnmf[t - 128] = parse_mask(nn_mask, flag, b * PP + (t - 128));
    }
    {   // nb/nn row stats: 64 rows x 4 quarter-threads, 4 float4 loads each
        int row = t >> 2, q4 = t & 3;
        int idx = (row < PP) ? nb_i[row] : nn_i[row - PP];
        const float* rp = u2e + (size_t)idx * DD + 16 * q4;
        float s = 0.0f;
        #pragma unroll
        for (int q = 0; q < 4; ++q) {
            float4 e  = *(const float4*)(rp + 4 * q);
            float4 uu = *(const float4*)(u_s + 16 * q4 + 4 * q);
            float dx = e.x - uu.x, dy = e.y - uu.y, dz = e.z - uu.z, dw = e.w - uu.w;
            s += dx * dx + dy * dy + dz * dz + dw * dw;
        }
        s += __shfl_xor(s, 1);
        s += __shfl_xor(s, 2);
        if (q4 == 0) { if (row < PP) d1sA[row] = s; else d2sA[row - PP] = s; }
    }
    #pragma unroll
    for (int r = 0; r < 6; ++r) {
        short4 s4 = make_short4(f2bf(ch[r].x), f2bf(ch[r].y), f2bf(ch[r].z), f2bf(ch[r].w));
        *(short4*)(pn_bf + dstRow[r] * BSTR + 4 * dstQ[r]) = s4;
    }
    __syncthreads();

    // ---- Step 3: MFMA Gram (waves 0,1) | n stats (wave 2) | p stats + sort (wave 3)
    if (w < 2) {
        f32x16 acc;
        #pragma unroll
        for (int i = 0; i < 16; ++i) acc[i] = 0.0f;
        const int lr = lane & 31;
        const int hi = lane >> 5;
        const short* ap = pn_bf + lr * BSTR;                    // P row (A: m = lane&31)
        const short* bp = pn_bf + (PP + 32 * w + lr) * BSTR;    // N row (B: n = lane&31)
        #pragma unroll
        for (int c = 0; c < 4; ++c) {
            const int d0 = 16 * c + 8 * hi;                     // k = 8*(lane>>5)+e
            bf16x8 a = *(const bf16x8*)(ap + d0);
            bf16x8 bfr = *(const bf16x8*)(bp + d0);
            acc = __builtin_amdgcn_mfma_f32_32x32x16_bf16(a, bfr, acc, 0, 0, 0);
        }
        #pragma unroll
        for (int r = 0; r < 16; ++r) {
            const int m = (r & 3) + 8 * (r >> 2) + 4 * hi;      // verified C/D mapping
            s_lds[m * SSTR + 32 * w + lr] = acc[r];
        }
    } else if (w == 2) {                                        // n-row stats (exact fp32)
        const int k = lane;
        const float* rp = v2e + (size_t)neg_i[k] * DD;
        float sd = 0.0f, sq = 0.0f;
        #pragma unroll
        for (int q = 0; q < 16; ++q) {
            float4 e  = *(const float4*)(rp + 4 * q);
            float4 uu = *(const float4*)(u_s + 4 * q);
            float dx = e.x - uu.x, dy = e.y - uu.y, dz = e.z - uu.z, dw = e.w - uu.w;
            sd += dx * dx + dy * dy + dz * dz + dw * dw;
            sq += e.x * e.x + e.y * e.y + e.z * e.z + e.w * e.w;
        }
        d2[k] = sd; n2s[k] = sq;
    } else {                                                    // wave 3
        if (lane < PP) {                                        // p-row stats
            const float* rp = v2e + (size_t)pos_i[lane] * DD;
            float sd = 0.0f, sq = 0.0f;
            #pragma unroll
            for (int q = 0; q < 16; ++q) {
                float4 e  = *(const float4*)(rp + 4 * q);
                float4 uu = *(const float4*)(u_s + 4 * q);
                float dx = e.x - uu.x, dy = e.y - uu.y, dz = e.z - uu.z, dw = e.w - uu.w;
                sd += dx * dx + dy * dy + dz * dz + dw * dw;
                sq += e.x * e.x + e.y * e.y + e.z * e.z + e.w * e.w;
            }
            d1[lane] = sd; p2s[lane] = sq;
        } else {                                                // sort + suffix scan
            const int l2 = lane - PP;
            float vj = mvp[l2];
            int r = 0;
            #pragma unroll
            for (int j = 0; j < PP; ++j) {
                float o = mvp[j];
                r += (o < vj || (o == vj && j < l2)) ? 1 : 0;
            }
            s_srt[r] = vj;
            __threadfence_block();
            float y = s_srt[l2];
            #pragma unroll
            for (int d = 1; d < PP; d <<= 1) {
                float z = __shfl_down(y, d);
                if (l2 + d < PP) y += z;
            }
            S_suf[l2] = y;
            if (l2 == 0) S_suf[PP] = 0.0f;
        }
    }
    __syncthreads();

    // ---- Epilogue: closed-form hinge over S from LDS ---------------------
    const float m_u = sc[0], m_s = sc[1];
    const float s31 = s_srt[PP - 1];
    const int kb = t & 15;          // k = kb + 16c
    const int ib = t >> 4;          // i = ib + 16a
    float loss = 0.0f;
    #pragma unroll
    for (int a = 0; a < 2; ++a) {
        const int i = ib + 16 * a;
        const float d1i = d1[i], p2i = p2s[i], pmi = pmf[i];
        #pragma unroll
        for (int c = 0; c < 4; ++c) {
            const int k = kb + 16 * c;
            const float Sik = s_lds[i * SSTR + k];
            const float cc = d1i - (p2i + n2s[k] - 2.0f * Sik);
            const float v = -cc;
            int t0 = 0;
            #pragma unroll
            for (int st = 16; st > 0; st >>= 1)
                t0 += (s_srt[t0 + st - 1] <= v) ? st : 0;
            t0 += (s31 <= v) ? 1 : 0;
            const float inner = S_suf[t0] + (float)(PP - t0) * cc;
            const float uvh = fmaxf(m_u + d1i - d2[k], 0.0f);
            loss += pmi * nmf[k] * (inner + uvh);
        }
    }

    // uu: 1024 pairs, 4 per thread
    #pragma unroll
    for (int rr = 0; rr < 4; ++rr) {
        int pid = t + 256 * rr;
        int i = pid >> 5, k = pid & 31;
        loss += nbmf[i] * nnmf[k] * fmaxf(m_s + d1sA[i] - d2sA[k], 0.0f);
    }

    // ---- Block reduction --------------------------------------------------
    float a2 = (t < PP) ? mv_arr[t] * pmf[t] : 0.0f;
    float a3 = (t < PP) ? pmf[t] : 0.0f;
    #pragma unroll
    for (int m = 1; m < 64; m <<= 1) {
        loss += __shfl_xor(loss, m);
        a2   += __shfl_xor(a2, m);
        a3   += __shfl_xor(a3, m);
    }
    if (lane == 0) { red[w][0] = loss; red[w][1] = a2; red[w][2] = a3; }
    __syncthreads();
    if (t == 0) {
        float S0 = 0, S2 = 0, S3 = 0;
        for (int i = 0; i < 4; ++i) { S0 += red[i][0]; S2 += red[i][1]; S3 += red[i][2]; }
        ws[0 * BB + b] = S0;
        ws[1 * BB + b] = sc[0];
        ws[2 * BB + b] = S2;
        ws[3 * BB + b] = S3;
        ws[4 * BB + b] = sc[1];
    }
}

// ---------------------------------------------------------------------------
// Finalize: deterministic tree reduction of the 5 per-block partial arrays.
// ---------------------------------------------------------------------------
__global__ __launch_bounds__(256) void finalize_kernel(const float* __restrict__ ws,
                                                       float* __restrict__ out) {
    __shared__ float red[4][5];
    const int t = threadIdx.x, lane = t & 63, w = t >> 6;
    float s[5] = {0, 0, 0, 0, 0};
    for (int i = t; i < BB; i += 256)
        #pragma unroll
        for (int a = 0; a < 5; ++a) s[a] += ws[a * BB + i];
    #pragma unroll
    for (int m = 1; m < 64; m <<= 1)
        #pragma unroll
        for (int a = 0; a < 5; ++a) s[a] += __shfl_xor(s[a], m);
    if (lane == 0)
        #pragma unroll
        for (int a = 0; a < 5; ++a) red[w][a] = s[a];
    __syncthreads();
    if (t == 0) {
        float S[5];
        #pragma unroll
        for (int a = 0; a < 5; ++a) {
            S[a] = 0;
            for (int i = 0; i < 4; ++i) S[a] += red[i][a];
        }
        float loss_am = S[1] / (float)BB + S[2] / S[3] + S[4] / (float)BB;
        out[0] = S[0] + W2c * loss_am;
    }
}

extern "C" void kernel_launch(void* const* d_in, const int* in_sizes, int n_in,
                              void* d_out, int out_size, void* d_ws, size_t ws_size,
                              hipStream_t stream) {
    const float* u2e       = (const float*)d_in[0];
    const float* v2e       = (const float*)d_in[1];
    const float* margin_uv = (const float*)d_in[2];
    const float* margin_vv = (const float*)d_in[3];
    const float* margin_uu = (const float*)d_in[4];
    const int*   train_u   = (const int*)d_in[5];
    const int*   pos_idx   = (const int*)d_in[6];
    const int*   neg_idx   = (const int*)d_in[7];
    const int*   nb_idx    = (const int*)d_in[8];
    const int*   nn_idx    = (const int*)d_in[9];
    const void*  pos_mask  = d_in[10];
    const void*  neg_mask  = d_in[11];
    const void*  nb_mask   = d_in[12];
    const void*  nn_mask   = d_in[13];

    float* ws  = (float*)d_ws;
    float* out = (float*)d_out;

    loss_kernel<<<BB, 256, 0, stream>>>(u2e, v2e, margin_uv, margin_vv, margin_uu,
                                        train_u, pos_idx, neg_idx, nb_idx, nn_idx,
                                        pos_mask, neg_mask, nb_mask, nn_mask, ws);
    finalize_kernel<<<1, 256, 0, stream>>>(ws, out);
}

// Round 6
// 21.370 us; speedup vs baseline: 5.9445x; 1.0059x over previous
//
#include <hip/hip_runtime.h>
#include <cfloat>

#define BB   1024
#define PP   32
#define NNEG 64
#define DD   64
#define BSTR 72   // bf16 LDS row stride (144 B, 16B-aligned)
#define SSTR 66   // s_lds row stride in floats

static constexpr float W2c = 0.1f;

typedef __attribute__((ext_vector_type(8)))  short bf16x8;
typedef __attribute__((ext_vector_type(16))) float f32x16;

__device__ __forceinline__ short f2bf(float f) {   // RNE fp32->bf16
    unsigned u = __float_as_uint(f);
    unsigned r = (u + 0x7fffu + ((u >> 16) & 1u)) >> 16;
    return (short)r;
}

__device__ __forceinline__ float parse_mask(const void* p, int flag, int j) {
    if (flag == 1) return ((const unsigned char*)p)[j] ? 1.0f : 0.0f;
    if (flag == 2) return (((const float*)p)[j] != 0.0f) ? 1.0f : 0.0f;
    return ((const int*)p)[j] ? 1.0f : 0.0f;
}

// ---------------------------------------------------------------------------
// One block per batch element b; 512 threads (8 waves) for 32 waves/CU.
// p/n row stats come from in-register gather partials + 16-lane shuffles
// (no global re-read on the critical path). Gram via MFMA (waves 0-1).
// ---------------------------------------------------------------------------
__global__ __launch_bounds__(512, 8) void loss_kernel(
    const float* __restrict__ u2e, const float* __restrict__ v2e,
    const float* __restrict__ margin_uv, const float* __restrict__ margin_vv,
    const float* __restrict__ margin_uu,
    const int* __restrict__ train_u, const int* __restrict__ pos_idx,
    const int* __restrict__ neg_idx, const int* __restrict__ nb_idx,
    const int* __restrict__ nn_idx,
    const void* __restrict__ pos_mask, const void* __restrict__ neg_mask,
    const void* __restrict__ nb_mask, const void* __restrict__ nn_mask,
    float* __restrict__ ws) {

    const int b = blockIdx.x;
    const int t = threadIdx.x;
    const int lane = t & 63;
    const int w = t >> 6;

    __shared__ __align__(16) short pn_bf[96 * BSTR];   // rows 0..31 p, 32..95 n (bf16)
    __shared__ __align__(16) float s_lds[PP * SSTR];   // Gram output S[i][k]
    __shared__ __align__(16) float u_s[DD];
    __shared__ float d1[PP], p2s[PP], d2[NNEG], n2s[NNEG], d1sA[PP], d2sA[PP];
    __shared__ float pmf[PP], nmf[NNEG], nbmf[PP], nnmf[PP];
    __shared__ float mvp[PP], mv_arr[PP], s_srt[PP], S_suf[PP + 1];
    __shared__ int   pos_i[PP], neg_i[NNEG], nb_i[PP], nn_i[PP];
    __shared__ float sc[2];
    __shared__ float red[8][3];
    __shared__ int   wflags[8][2];

    const int tu = train_u[b];

    // ---- Step 1: mask-layout sniff, indices, u row -----------------------
    {
        unsigned int mw = ((const unsigned int*)pos_mask)[t];  // 2KB < any layout size
        int f32hit  = (mw == 0x3f800000u) ? 1 : 0;
        int bytehit = (!f32hit && (mw & 0xFFFFFF00u)) ? 1 : 0;
        int wf = __any(f32hit) ? 1 : 0;
        int wb = __any(bytehit) ? 1 : 0;
        if (lane == 0) { wflags[w][0] = wf; wflags[w][1] = wb; }
    }
    if (t < DD) u_s[t] = u2e[(size_t)tu * DD + t];
    if (t < PP)              pos_i[t]       = pos_idx[b * PP + t];
    else if (t < 96)         neg_i[t - PP]  = neg_idx[b * NNEG + (t - PP)];
    else if (t < 128)        nb_i[t - 96]   = nb_idx[b * PP + (t - 96)];
    else if (t < 160)        nn_i[t - 128]  = nn_idx[b * PP + (t - 128)];
    if (t == 0) { sc[0] = margin_uv[tu]; sc[1] = margin_uu[tu]; }
    __syncthreads();

    const int flag = (wflags[0][0] | wflags[1][0] | wflags[2][0] | wflags[3][0] |
                      wflags[4][0] | wflags[5][0] | wflags[6][0] | wflags[7][0]) ? 2
                   : ((wflags[0][1] | wflags[1][1] | wflags[2][1] | wflags[3][1] |
                       wflags[4][1] | wflags[5][1] | wflags[6][1] | wflags[7][1]) ? 1 : 0);

    // ---- Step 2: gather p/n chunks + in-register stats + masks + nb/nn ---
    // Thread t owns column-chunk q=t&15 of rows R0, R0+32, R0+64 (R0=t>>4).
    const int q  = t & 15;
    const int R0 = t >> 4;
    const float4 u4 = *(const float4*)(u_s + 4 * q);
    float4 ch[3];
    float sdp[3], sqp[3];
    #pragma unroll
    for (int r = 0; r < 3; ++r) {
        const int R = R0 + 32 * r;
        const int gidx = (R < PP) ? pos_i[R] : neg_i[R - PP];
        ch[r] = *(const float4*)(v2e + (size_t)gidx * DD + 4 * q);
        float dx = ch[r].x - u4.x, dy = ch[r].y - u4.y,
              dz = ch[r].z - u4.z, dw = ch[r].w - u4.w;
        sdp[r] = dx * dx + dy * dy + dz * dz + dw * dw;
        sqp[r] = ch[r].x * ch[r].x + ch[r].y * ch[r].y
               + ch[r].z * ch[r].z + ch[r].w * ch[r].w;
    }
    #pragma unroll
    for (int m = 1; m < 16; m <<= 1) {
        #pragma unroll
        for (int r = 0; r < 3; ++r) {
            sdp[r] += __shfl_xor(sdp[r], m);
            sqp[r] += __shfl_xor(sqp[r], m);
        }
    }
    if (q == 0) {
        #pragma unroll
        for (int r = 0; r < 3; ++r) {
            const int R = R0 + 32 * r;
            if (R < PP) { d1[R] = sdp[r]; p2s[R] = sqp[r]; }
            else        { d2[R - PP] = sdp[r]; n2s[R - PP] = sqp[r]; }
        }
    }
    if (t < PP) {
        float pm = parse_mask(pos_mask, flag, b * PP + t);
        float mv = margin_vv[pos_i[t]];
        pmf[t] = pm; mv_arr[t] = mv;
        mvp[t] = (pm != 0.0f) ? mv : -FLT_MAX;
    } else if (t < 96) {
        nmf[t - PP] = parse_mask(neg_mask, flag, b * NNEG + (t - PP));
    } else if (t < 128) {
        nbmf[t - 96] = parse_mask(nb_mask, flag, b * PP + (t - 96));
    } else if (t < 160) {
        nnmf[t - 128] = parse_mask(nn_mask, flag, b * PP + (t - 128));
    }
    {   // nb/nn stats: 64 rows x 8 threads, 2 float4 each, 3-step shuffle
        const int row = t >> 3, sub = t & 7;
        const int idx = (row < PP) ? nb_i[row] : nn_i[row - PP];
        const float* rp = u2e + (size_t)idx * DD + 8 * sub;
        float4 e0 = *(const float4*)(rp);
        float4 e1 = *(const float4*)(rp + 4);
        float4 v0 = *(const float4*)(u_s + 8 * sub);
        float4 v1 = *(const float4*)(u_s + 8 * sub + 4);
        float dx = e0.x - v0.x, dy = e0.y - v0.y, dz = e0.z - v0.z, dw = e0.w - v0.w;
        float s = dx * dx + dy * dy + dz * dz + dw * dw;
        dx = e1.x - v1.x; dy = e1.y - v1.y; dz = e1.z - v1.z; dw = e1.w - v1.w;
        s += dx * dx + dy * dy + dz * dz + dw * dw;
        s += __shfl_xor(s, 1);
        s += __shfl_xor(s, 2);
        s += __shfl_xor(s, 4);
        if (sub == 0) { if (row < PP) d1sA[row] = s; else d2sA[row - PP] = s; }
    }
    #pragma unroll
    for (int r = 0; r < 3; ++r) {
        const int R = R0 + 32 * r;
        short4 s4 = make_short4(f2bf(ch[r].x), f2bf(ch[r].y), f2bf(ch[r].z), f2bf(ch[r].w));
        *(short4*)(pn_bf + R * BSTR + 4 * q) = s4;
    }
    __syncthreads();

    // ---- Step 3: MFMA Gram (waves 0,1) | sort + suffix scan (wave 2) -----
    if (w < 2) {
        f32x16 acc;
        #pragma unroll
        for (int i = 0; i < 16; ++i) acc[i] = 0.0f;
        const int lr = lane & 31;
        const int hi = lane >> 5;
        const short* ap = pn_bf + lr * BSTR;                    // A: m = lane&31
        const short* bp = pn_bf + (PP + 32 * w + lr) * BSTR;    // B: n = lane&31
        #pragma unroll
        for (int c = 0; c < 4; ++c) {
            const int d0 = 16 * c + 8 * hi;                     // k = 8*(lane>>5)+e
            bf16x8 a   = *(const bf16x8*)(ap + d0);
            bf16x8 bfr = *(const bf16x8*)(bp + d0);
            acc = __builtin_amdgcn_mfma_f32_32x32x16_bf16(a, bfr, acc, 0, 0, 0);
        }
        #pragma unroll
        for (int r = 0; r < 16; ++r) {
            const int m = (r & 3) + 8 * (r >> 2) + 4 * hi;      // verified C/D mapping
            s_lds[m * SSTR + 32 * w + lr] = acc[r];
        }
    } else if (w == 2 && lane < PP) {
        float vj = mvp[lane];
        int r = 0;
        #pragma unroll
        for (int j = 0; j < PP; ++j) {
            float o = mvp[j];
            r += (o < vj || (o == vj && j < lane)) ? 1 : 0;
        }
        s_srt[r] = vj;
        __threadfence_block();
        float y = s_srt[lane];
        #pragma unroll
        for (int d = 1; d < PP; d <<= 1) {
            float z = __shfl_down(y, d);
            if (lane + d < PP) y += z;
        }
        S_suf[lane] = y;
        if (lane == 0) S_suf[PP] = 0.0f;
    }
    __syncthreads();

    // ---- Epilogue: closed-form hinge over S; 4 (i,k) pairs per thread ----
    const float m_u = sc[0], m_s = sc[1];
    const float s31 = s_srt[PP - 1];
    const int kb = t & 15;
    const int i  = t >> 4;          // 0..31
    const float d1i = d1[i], p2i = p2s[i], pmi = pmf[i];
    float loss = 0.0f;
    #pragma unroll
    for (int c = 0; c < 4; ++c) {
        const int k = kb + 16 * c;
        const float Sik = s_lds[i * SSTR + k];
        const float cc = d1i - (p2i + n2s[k] - 2.0f * Sik);
        const float v = -cc;
        int t0 = 0;
        #pragma unroll
        for (int st = 16; st > 0; st >>= 1)
            t0 += (s_srt[t0 + st - 1] <= v) ? st : 0;
        t0 += (s31 <= v) ? 1 : 0;
        const float inner = S_suf[t0] + (float)(PP - t0) * cc;
        const float uvh = fmaxf(m_u + d1i - d2[k], 0.0f);
        loss += pmi * nmf[k] * (inner + uvh);
    }

    // uu: 1024 pairs, 2 per thread
    #pragma unroll
    for (int rr = 0; rr < 2; ++rr) {
        int pid = t + 512 * rr;
        int ii = pid >> 5, k = pid & 31;
        loss += nbmf[ii] * nnmf[k] * fmaxf(m_s + d1sA[ii] - d2sA[k], 0.0f);
    }

    // ---- Block reduction --------------------------------------------------
    float a2 = (t < PP) ? mv_arr[t] * pmf[t] : 0.0f;
    float a3 = (t < PP) ? pmf[t] : 0.0f;
    #pragma unroll
    for (int m = 1; m < 64; m <<= 1) {
        loss += __shfl_xor(loss, m);
        a2   += __shfl_xor(a2, m);
        a3   += __shfl_xor(a3, m);
    }
    if (lane == 0) { red[w][0] = loss; red[w][1] = a2; red[w][2] = a3; }
    __syncthreads();
    if (t == 0) {
        float S0 = 0, S2 = 0, S3 = 0;
        #pragma unroll
        for (int i2 = 0; i2 < 8; ++i2) { S0 += red[i2][0]; S2 += red[i2][1]; S3 += red[i2][2]; }
        ws[0 * BB + b] = S0;
        ws[1 * BB + b] = sc[0];
        ws[2 * BB + b] = S2;
        ws[3 * BB + b] = S3;
        ws[4 * BB + b] = sc[1];
    }
}

// ---------------------------------------------------------------------------
// Finalize: deterministic tree reduction of the 5 per-block partial arrays.
// ---------------------------------------------------------------------------
__global__ __launch_bounds__(256) void finalize_kernel(const float* __restrict__ ws,
                                                       float* __restrict__ out) {
    __shared__ float red[4][5];
    const int t = threadIdx.x, lane = t & 63, w = t >> 6;
    float s[5] = {0, 0, 0, 0, 0};
    for (int i = t; i < BB; i += 256)
        #pragma unroll
        for (int a = 0; a < 5; ++a) s[a] += ws[a * BB + i];
    #pragma unroll
    for (int m = 1; m < 64; m <<= 1)
        #pragma unroll
        for (int a = 0; a < 5; ++a) s[a] += __shfl_xor(s[a], m);
    if (lane == 0)
        #pragma unroll
        for (int a = 0; a < 5; ++a) red[w][a] = s[a];
    __syncthreads();
    if (t == 0) {
        float S[5];
        #pragma unroll
        for (int a = 0; a < 5; ++a) {
            S[a] = 0;
            for (int i = 0; i < 4; ++i) S[a] += red[i][a];
        }
        float loss_am = S[1] / (float)BB + S[2] / S[3] + S[4] / (float)BB;
        out[0] = S[0] + W2c * loss_am;
    }
}

extern "C" void kernel_launch(void* const* d_in, const int* in_sizes, int n_in,
                              void* d_out, int out_size, void* d_ws, size_t ws_size,
                              hipStream_t stream) {
    const float* u2e       = (const float*)d_in[0];
    const float* v2e       = (const float*)d_in[1];
    const float* margin_uv = (const float*)d_in[2];
    const float* margin_vv = (const float*)d_in[3];
    const float* margin_uu = (const float*)d_in[4];
    const int*   train_u   = (const int*)d_in[5];
    const int*   pos_idx   = (const int*)d_in[6];
    const int*   neg_idx   = (const int*)d_in[7];
    const int*   nb_idx    = (const int*)d_in[8];
    const int*   nn_idx    = (const int*)d_in[9];
    const void*  pos_mask  = d_in[10];
    const void*  neg_mask  = d_in[11];
    const void*  nb_mask   = d_in[12];
    const void*  nn_mask   = d_in[13];

    float* ws  = (float*)d_ws;
    float* out = (float*)d_out;

    loss_kernel<<<BB, 512, 0, stream>>>(u2e, v2e, margin_uv, margin_vv, margin_uu,
                                        train_u, pos_idx, neg_idx, nb_idx, nn_idx,
                                        pos_mask, neg_mask, nb_mask, nn_mask, ws);
    finalize_kernel<<<1, 256, 0, stream>>>(ws, out);
}